// Round 3
// baseline (485.428 us; speedup 1.0000x reference)
//
#include <hip/hip_runtime.h>
#include <hip/hip_bf16.h>

// BCE: mean over 67.1M elements of -(target ? log(p) : log(1-p)).
// Memory-bound streaming reduction: 537 MB in -> scalar out. Floor ~85us.
// R3 changes vs R2: 4x unroll / 4 independent accumulator chains so each
// thread keeps 8 x b128 loads (512 B) in flight -> ~16 KB/CU outstanding,
// covering ~900cy HBM latency at 10.2 B/cy/CU demand.

#define BLOCKS 2048
#define THREADS 256

typedef float  f32x4 __attribute__((ext_vector_type(4)));
typedef int    i32x4 __attribute__((ext_vector_type(4)));

__device__ __forceinline__ float bce4(f32x4 pv, i32x4 tv) {
  float s = 0.0f;
  s += __logf(tv.x ? pv.x : 1.0f - pv.x);
  s += __logf(tv.y ? pv.y : 1.0f - pv.y);
  s += __logf(tv.z ? pv.z : 1.0f - pv.z);
  s += __logf(tv.w ? pv.w : 1.0f - pv.w);
  return s;
}

__global__ __launch_bounds__(THREADS) void bce_partial_kernel(
    const float* __restrict__ p, const int* __restrict__ t,
    double* __restrict__ partial, long long nvec, long long n) {
  long long tid = (long long)blockIdx.x * blockDim.x + threadIdx.x;
  long long stride = (long long)gridDim.x * blockDim.x;

  const f32x4* p4 = reinterpret_cast<const f32x4*>(p);
  const i32x4* t4 = reinterpret_cast<const i32x4*>(t);

  float s0 = 0.0f, s1 = 0.0f, s2 = 0.0f, s3 = 0.0f;
  long long i = tid;
  // 4x-unrolled main loop: issue all 8 independent b128 loads before any
  // consumption; 4 independent accumulator chains.
  for (; i + 3 * stride < nvec; i += 4 * stride) {
    f32x4 pa = __builtin_nontemporal_load(&p4[i]);
    f32x4 pb = __builtin_nontemporal_load(&p4[i + stride]);
    f32x4 pc = __builtin_nontemporal_load(&p4[i + 2 * stride]);
    f32x4 pd = __builtin_nontemporal_load(&p4[i + 3 * stride]);
    i32x4 ta = __builtin_nontemporal_load(&t4[i]);
    i32x4 tb = __builtin_nontemporal_load(&t4[i + stride]);
    i32x4 tc = __builtin_nontemporal_load(&t4[i + 2 * stride]);
    i32x4 td = __builtin_nontemporal_load(&t4[i + 3 * stride]);
    s0 += bce4(pa, ta);
    s1 += bce4(pb, tb);
    s2 += bce4(pc, tc);
    s3 += bce4(pd, td);
  }
  for (; i < nvec; i += stride) {
    f32x4 pa = __builtin_nontemporal_load(&p4[i]);
    i32x4 ta = __builtin_nontemporal_load(&t4[i]);
    s0 += bce4(pa, ta);
  }
  float sum = (s0 + s1) + (s2 + s3);

  // scalar tail (n not divisible by 4) — handled by first threads
  long long tail_start = nvec * 4;
  long long tail_n = n - tail_start;
  if (tid < tail_n) {
    long long j = tail_start + tid;
    sum += __logf(t[j] ? p[j] : 1.0f - p[j]);
  }

  // wave64 reduction (f32 fine: bounded terms per lane)
  for (int off = 32; off > 0; off >>= 1) sum += __shfl_down(sum, off);

  __shared__ float wsum[THREADS / 64];
  int lane = threadIdx.x & 63;
  int wave = threadIdx.x >> 6;
  if (lane == 0) wsum[wave] = sum;
  __syncthreads();
  if (threadIdx.x == 0) {
    double bsum = 0.0;
    #pragma unroll
    for (int w = 0; w < THREADS / 64; ++w) bsum += (double)wsum[w];
    partial[blockIdx.x] = bsum;  // every slot written every launch
  }
}

__global__ __launch_bounds__(256) void bce_final_kernel(
    const double* __restrict__ partial, int nparts, float* __restrict__ out,
    double inv_n) {
  double s = 0.0;
  for (int i = threadIdx.x; i < nparts; i += blockDim.x) s += partial[i];
  for (int off = 32; off > 0; off >>= 1) s += __shfl_down(s, off);
  __shared__ double wsum[4];
  int lane = threadIdx.x & 63;
  int wave = threadIdx.x >> 6;
  if (lane == 0) wsum[wave] = s;
  __syncthreads();
  if (threadIdx.x == 0) {
    double tot = wsum[0] + wsum[1] + wsum[2] + wsum[3];
    out[0] = (float)(-tot * inv_n);
  }
}

extern "C" void kernel_launch(void* const* d_in, const int* in_sizes, int n_in,
                              void* d_out, int out_size, void* d_ws, size_t ws_size,
                              hipStream_t stream) {
  const float* p = (const float*)d_in[0];
  const int* t = (const int*)d_in[1];
  float* out = (float*)d_out;
  double* partial = (double*)d_ws;

  long long n = (long long)in_sizes[0];
  long long nvec = n / 4;

  long long want = (nvec + THREADS - 1) / THREADS;
  int blocks = (int)(want < BLOCKS ? (want > 0 ? want : 1) : BLOCKS);

  bce_partial_kernel<<<blocks, THREADS, 0, stream>>>(p, t, partial, nvec, n);
  bce_final_kernel<<<1, 256, 0, stream>>>(partial, blocks, out, 1.0 / (double)n);
}